// Round 1
// baseline (1593.315 us; speedup 1.0000x reference)
//
#include <hip/hip_runtime.h>
#include <hip/hip_bf16.h>
#include <hip/hip_fp16.h>

#define NL 4
#define DM 1024
#define DI 2048
#define DS_N 16
#define DC 4
#define DTR 64
#define IN_DIM 256
#define OUT_DIM 128
#define BATCH 4096

typedef _Float16 half8 __attribute__((ext_vector_type(8)));
typedef float floatx4 __attribute__((ext_vector_type(4)));

__device__ __forceinline__ float silu_f(float x) {
    return x / (1.0f + __expf(-x));
}

struct EpiP {
    float* o32;
    _Float16* o16;
    _Float16* o16b;
    const float* bias;
    const float* cw;      // conv_w + l*DI*DC, index [n*DC+3]
    const float* cb;
    const float* dtb;
    const float* Dp;
    const float* BC;
    const _Float16* xc;
    const _Float16* zs;
};

// C[M x N] = A[M x K] * W[N x K]^T ; A fp16 (or fp32 if A32), W fp32.
// Tile 128x128, BK=32, 4 waves of 4x4 16x16x32 f16 MFMAs.
template<bool A32, int EPI>
__global__ __launch_bounds__(256) void gemm_k(
    const void* __restrict__ Ap, const float* __restrict__ W,
    int N, int K, int lda, EpiP ep)
{
    constexpr int BK = 32;
    __shared__ _Float16 As[128 * 40];
    __shared__ _Float16 Bs[128 * 40];
    const int tid  = threadIdx.x;
    const int lane = tid & 63;
    const int wave = tid >> 6;
    const int wm = (wave >> 1) * 64;
    const int wn = (wave & 1) * 64;
    const int lr = lane & 15;   // m (A) / n (B) / col (D)
    const int lq = lane >> 4;   // quad
    const long tm = (long)blockIdx.y * 128;
    const int  tn = blockIdx.x * 128;

    floatx4 acc[4][4];
#pragma unroll
    for (int i = 0; i < 4; i++)
#pragma unroll
        for (int j = 0; j < 4; j++) acc[i][j] = (floatx4)0.0f;

    const int sr = tid >> 1;          // staging row 0..127
    const int sc = (tid & 1) * 16;    // staging col {0,16}

    for (int k0 = 0; k0 < K; k0 += BK) {
        // ---- stage A (128 x 32 halves) ----
        if constexpr (A32) {
            const float* src = (const float*)Ap + (tm + sr) * (long)lda + k0 + sc;
            float4 f0 = *(const float4*)(src);
            float4 f1 = *(const float4*)(src + 4);
            float4 f2 = *(const float4*)(src + 8);
            float4 f3 = *(const float4*)(src + 12);
            half8 h0, h1;
            h0[0]=(_Float16)f0.x; h0[1]=(_Float16)f0.y; h0[2]=(_Float16)f0.z; h0[3]=(_Float16)f0.w;
            h0[4]=(_Float16)f1.x; h0[5]=(_Float16)f1.y; h0[6]=(_Float16)f1.z; h0[7]=(_Float16)f1.w;
            h1[0]=(_Float16)f2.x; h1[1]=(_Float16)f2.y; h1[2]=(_Float16)f2.z; h1[3]=(_Float16)f2.w;
            h1[4]=(_Float16)f3.x; h1[5]=(_Float16)f3.y; h1[6]=(_Float16)f3.z; h1[7]=(_Float16)f3.w;
            *(half8*)&As[sr * 40 + sc]     = h0;
            *(half8*)&As[sr * 40 + sc + 8] = h1;
        } else {
            const _Float16* src = (const _Float16*)Ap + (tm + sr) * (long)lda + k0 + sc;
            half8 v0 = *(const half8*)(src);
            half8 v1 = *(const half8*)(src + 8);
            *(half8*)&As[sr * 40 + sc]     = v0;
            *(half8*)&As[sr * 40 + sc + 8] = v1;
        }
        // ---- stage W fp32 -> fp16 (128 x 32) ----
        {
            int gn = tn + sr;
            float4 f0, f1, f2, f3;
            if (gn < N) {
                const float* src = W + (long)gn * K + k0 + sc;
                f0 = *(const float4*)(src);
                f1 = *(const float4*)(src + 4);
                f2 = *(const float4*)(src + 8);
                f3 = *(const float4*)(src + 12);
            } else {
                f0 = make_float4(0.f,0.f,0.f,0.f); f1 = f0; f2 = f0; f3 = f0;
            }
            half8 h0, h1;
            h0[0]=(_Float16)f0.x; h0[1]=(_Float16)f0.y; h0[2]=(_Float16)f0.z; h0[3]=(_Float16)f0.w;
            h0[4]=(_Float16)f1.x; h0[5]=(_Float16)f1.y; h0[6]=(_Float16)f1.z; h0[7]=(_Float16)f1.w;
            h1[0]=(_Float16)f2.x; h1[1]=(_Float16)f2.y; h1[2]=(_Float16)f2.z; h1[3]=(_Float16)f2.w;
            h1[4]=(_Float16)f3.x; h1[5]=(_Float16)f3.y; h1[6]=(_Float16)f3.z; h1[7]=(_Float16)f3.w;
            *(half8*)&Bs[sr * 40 + sc]     = h0;
            *(half8*)&Bs[sr * 40 + sc + 8] = h1;
        }
        __syncthreads();

        half8 af[4], bf[4];
#pragma unroll
        for (int i = 0; i < 4; i++)
            af[i] = *(const half8*)&As[(wm + i * 16 + lr) * 40 + lq * 8];
#pragma unroll
        for (int j = 0; j < 4; j++)
            bf[j] = *(const half8*)&Bs[(wn + j * 16 + lr) * 40 + lq * 8];
#pragma unroll
        for (int i = 0; i < 4; i++)
#pragma unroll
            for (int j = 0; j < 4; j++)
                acc[i][j] = __builtin_amdgcn_mfma_f32_16x16x32_f16(af[i], bf[j], acc[i][j], 0, 0, 0);
        __syncthreads();
    }

    // ---- epilogue ----
#pragma unroll
    for (int i = 0; i < 4; i++) {
#pragma unroll
        for (int p = 0; p < 4; p++) {
            long m = tm + wm + i * 16 + lq * 4 + p;
#pragma unroll
            for (int j = 0; j < 4; j++) {
                int n = tn + wn + j * 16 + lr;
                if (n >= N) continue;
                float v = acc[i][j][p];
                if constexpr (EPI == 0) {            // input: +bias -> h32, h16
                    v += ep.bias[n];
                    ep.o32[m * DM + n] = v;
                    ep.o16[m * DM + n] = (_Float16)v;
                } else if constexpr (EPI == 1) {     // inproj: conv+silu -> xc16 ; silu(z) -> zs16
                    if (n < DI) {
                        float s = v * ep.cw[n * DC + 3] + ep.cb[n];
                        ep.o16[m * DI + n] = (_Float16)silu_f(s);
                    } else {
                        ep.o16b[m * DI + (n - DI)] = (_Float16)silu_f(v);
                    }
                } else if constexpr (EPI == 2) {     // xproj -> xdbl16 (ld 96)
                    ep.o16[m * 96 + n] = (_Float16)v;
                } else if constexpr (EPI == 3) {     // dt: softplus, y = xc*(dt*BC+D)*zs -> y16 (in place on xc)
                    float dtv = v + ep.dtb[n];
                    dtv = (dtv > 20.0f) ? dtv : log1pf(__expf(dtv));
                    float y = (float)ep.xc[m * DI + n] * (dtv * ep.BC[m] + ep.Dp[n]) * (float)ep.zs[m * DI + n];
                    ep.o16[m * DI + n] = (_Float16)y;
                } else if constexpr (EPI == 4) {     // out GEMM -> ln_in fp32
                    ep.o32[m * DM + n] = v;
                } else {                              // final: +bias -> d_out
                    ep.o32[m * OUT_DIM + n] = v + ep.bias[n];
                }
            }
        }
    }
}

__global__ void bc_k(const _Float16* __restrict__ xdbl, float* __restrict__ BC) {
    int b = blockIdx.x * blockDim.x + threadIdx.x;
    if (b >= BATCH) return;
    const _Float16* p = xdbl + (long)b * 96 + DTR;
    float s = 0.0f;
#pragma unroll
    for (int n = 0; n < DS_N; n++) s += (float)p[n] * (float)p[DS_N + n];
    BC[b] = s;
}

__global__ __launch_bounds__(256) void ln_k(
    const float* __restrict__ xin, const float* __restrict__ g, const float* __restrict__ b,
    float* __restrict__ h32, _Float16* __restrict__ h16)
{
    long row = blockIdx.x;
    const float* x = xin + row * DM;
    int t = threadIdx.x;
    float v[4];
    float s = 0.0f, ss = 0.0f;
#pragma unroll
    for (int i = 0; i < 4; i++) {
        v[i] = x[t + i * 256];
        s += v[i];
        ss += v[i] * v[i];
    }
#pragma unroll
    for (int o = 32; o > 0; o >>= 1) {
        s  += __shfl_down(s, o, 64);
        ss += __shfl_down(ss, o, 64);
    }
    __shared__ float rs[4], rss[4];
    int wv = t >> 6, ln = t & 63;
    if (ln == 0) { rs[wv] = s; rss[wv] = ss; }
    __syncthreads();
    if (t == 0) {
        float S  = rs[0] + rs[1] + rs[2] + rs[3];
        float SS = rss[0] + rss[1] + rss[2] + rss[3];
        float mu = S / (float)DM;
        float var = SS / (float)DM - mu * mu;
        rs[0]  = mu;
        rss[0] = rsqrtf(var + 1e-5f);
    }
    __syncthreads();
    float mu = rs[0], rstd = rss[0];
#pragma unroll
    for (int i = 0; i < 4; i++) {
        int c = t + i * 256;
        float hv = h32[row * DM + c] + (v[i] - mu) * rstd * g[c] + b[c];
        h32[row * DM + c] = hv;
        h16[row * DM + c] = (_Float16)hv;
    }
}

extern "C" void kernel_launch(void* const* d_in, const int* in_sizes, int n_in,
                              void* d_out, int out_size, void* d_ws, size_t ws_size,
                              hipStream_t stream) {
    const float* x         = (const float*)d_in[0];
    const float* inp_w     = (const float*)d_in[1];
    const float* inp_b     = (const float*)d_in[2];
    const float* in_proj_w = (const float*)d_in[3];
    const float* conv_w    = (const float*)d_in[4];
    const float* conv_b    = (const float*)d_in[5];
    const float* xproj_w   = (const float*)d_in[6];
    const float* dt_w      = (const float*)d_in[7];
    const float* dt_b      = (const float*)d_in[8];
    // d_in[9] = A_log : provably unused when L==1 (h0 = 0)
    const float* D_param   = (const float*)d_in[10];
    const float* out_w     = (const float*)d_in[11];
    const float* ln_g      = (const float*)d_in[12];
    const float* ln_b      = (const float*)d_in[13];
    const float* outp_w    = (const float*)d_in[14];
    const float* outp_b    = (const float*)d_in[15];

    char* ws = (char*)d_ws;
    float*    h32  = (float*)   (ws);                    // 16 MB
    _Float16* h16  = (_Float16*)(ws + (16u << 20));      //  8 MB
    _Float16* xc16 = (_Float16*)(ws + (24u << 20));      // 16 MB (becomes y16 in place)
    _Float16* zs16 = (_Float16*)(ws + (40u << 20));      // 16 MB (dead after dt GEMM)
    float*    lnin = (float*)   (ws + (40u << 20));      // aliases zs16 region
    _Float16* xdbl = (_Float16*)(ws + (56u << 20));      // 768 KB
    float*    BC   = (float*)   (ws + (57u << 20));      // 16 KB

    dim3 blk(256);
    EpiP ep;

    // input GEMM: h = x @ inp_w^T + inp_b   (M=4096, N=1024, K=256)
    ep = EpiP{}; ep.bias = inp_b; ep.o32 = h32; ep.o16 = h16;
    gemm_k<true, 0><<<dim3(DM / 128, BATCH / 128), blk, 0, stream>>>(x, inp_w, DM, IN_DIM, IN_DIM, ep);

    for (int l = 0; l < NL; l++) {
        // inproj: xz = h @ in_w^T ; fused conv+silu -> xc16, silu(z) -> zs16  (N=4096, K=1024)
        ep = EpiP{}; ep.o16 = xc16; ep.o16b = zs16;
        ep.cw = conv_w + (size_t)l * DI * DC; ep.cb = conv_b + (size_t)l * DI;
        gemm_k<false, 1><<<dim3(2 * DI / 128, BATCH / 128), blk, 0, stream>>>(
            h16, in_proj_w + (size_t)l * 2 * DI * DM, 2 * DI, DM, DM, ep);

        // xproj: x_dbl = xc @ xp_w^T   (N=96, K=2048)
        ep = EpiP{}; ep.o16 = xdbl;
        gemm_k<false, 2><<<dim3(1, BATCH / 128), blk, 0, stream>>>(
            xc16, xproj_w + (size_t)l * (DTR + 2 * DS_N) * DI, DTR + 2 * DS_N, DI, DI, ep);

        // BC[b] = Bm . Cm
        bc_k<<<dim3(BATCH / 256), blk, 0, stream>>>(xdbl, BC);

        // dt GEMM + fused scan-collapse epilogue -> y16 (in place over xc16)  (N=2048, K=64)
        ep = EpiP{}; ep.o16 = xc16;
        ep.dtb = dt_b + (size_t)l * DI; ep.Dp = D_param + (size_t)l * DI;
        ep.BC = BC; ep.xc = xc16; ep.zs = zs16;
        gemm_k<false, 3><<<dim3(DI / 128, BATCH / 128), blk, 0, stream>>>(
            xdbl, dt_w + (size_t)l * DI * DTR, DI, DTR, 96, ep);

        // out GEMM: lnin = y @ ow^T   (N=1024, K=2048)
        ep = EpiP{}; ep.o32 = lnin;
        gemm_k<false, 4><<<dim3(DM / 128, BATCH / 128), blk, 0, stream>>>(
            xc16, out_w + (size_t)l * DM * DI, DM, DI, DI, ep);

        // LayerNorm + residual -> h32, h16
        ln_k<<<dim3(BATCH), blk, 0, stream>>>(
            lnin, ln_g + (size_t)l * DM, ln_b + (size_t)l * DM, h32, h16);
    }

    // final: out = h @ outp_w^T + outp_b   (N=128, K=1024)
    ep = EpiP{}; ep.bias = outp_b; ep.o32 = (float*)d_out;
    gemm_k<false, 5><<<dim3(1, BATCH / 128), blk, 0, stream>>>(h16, outp_w, OUT_DIM, DM, DM, ep);
}

// Round 2
// 1466.082 us; speedup vs baseline: 1.0868x; 1.0868x over previous
//
#include <hip/hip_runtime.h>
#include <hip/hip_bf16.h>
#include <hip/hip_fp16.h>

#define NL 4
#define DM 1024
#define DI 2048
#define DS_N 16
#define DC 4
#define DTR 64
#define IN_DIM 256
#define OUT_DIM 128
#define BATCH 4096

typedef _Float16 half8 __attribute__((ext_vector_type(8)));
typedef float floatx4 __attribute__((ext_vector_type(4)));

// element offsets into the fp16 arena (x + all weights, concatenated)
#define E_X      0L
#define E_INPW   (E_X + (long)BATCH * IN_DIM)             // 1048576
#define E_INPROJ (E_INPW + (long)DM * IN_DIM)             // 1310720
#define E_XPROJ  (E_INPROJ + (long)NL * 2 * DI * DM)      // 18087936
#define E_DTW    (E_XPROJ + (long)NL * (DTR + 2 * DS_N) * DI) // 18874368
#define E_OUTW   (E_DTW + (long)NL * DI * DTR)            // 19398656
#define E_OUTPW  (E_OUTW + (long)NL * DM * DI)            // 27787264
#define E_TOT    (E_OUTPW + (long)OUT_DIM * DM)           // 27918336

__device__ __forceinline__ float silu_f(float x) {
    return x / (1.0f + __expf(-x));
}

__device__ __forceinline__ void gload_lds16(const _Float16* g, const _Float16* l) {
    __builtin_amdgcn_global_load_lds(
        (const __attribute__((address_space(1))) void*)(uintptr_t)g,
        (__attribute__((address_space(3))) void*)(uintptr_t)l,
        16, 0, 0);
}

// fp32 -> fp16 arena conversion (x + all weights). 8 elems/thread.
__global__ __launch_bounds__(256) void cvt_k(
    const float* __restrict__ x, const float* __restrict__ inp_w,
    const float* __restrict__ in_proj_w, const float* __restrict__ xproj_w,
    const float* __restrict__ dt_w, const float* __restrict__ out_w,
    const float* __restrict__ outp_w, _Float16* __restrict__ dst)
{
    long i = ((long)blockIdx.x * 256 + threadIdx.x) * 8;
    const float* s;
    if      (i < E_INPW)   s = x         + (i - E_X);
    else if (i < E_INPROJ) s = inp_w     + (i - E_INPW);
    else if (i < E_XPROJ)  s = in_proj_w + (i - E_INPROJ);
    else if (i < E_DTW)    s = xproj_w   + (i - E_XPROJ);
    else if (i < E_OUTW)   s = dt_w      + (i - E_DTW);
    else if (i < E_OUTPW)  s = out_w     + (i - E_OUTW);
    else                   s = outp_w    + (i - E_OUTPW);
    float4 a = *(const float4*)s;
    float4 b = *(const float4*)(s + 4);
    half8 h;
    h[0]=(_Float16)a.x; h[1]=(_Float16)a.y; h[2]=(_Float16)a.z; h[3]=(_Float16)a.w;
    h[4]=(_Float16)b.x; h[5]=(_Float16)b.y; h[6]=(_Float16)b.z; h[7]=(_Float16)b.w;
    *(half8*)(dst + i) = h;
}

struct EpiP {
    float* o32;
    _Float16* o16;
    _Float16* o16b;
    const float* bias;
    const float* cw;
    const float* cb;
    const float* dtb;
    const float* Dp;
    const float* BC;
    const _Float16* xc;
    const _Float16* zs;
};

// C[M x N] = A[M x K(lda)] * W[N x K]^T, both fp16. Tile 128x128, BK=32,
// 4 waves x (4x4) 16x16x32 MFMAs. global_load_lds(16B) staging into
// unpadded 128x32 LDS tiles with XOR chunk swizzle (2-way banks = free).
// grid.z = split-K factor; each z does kChunk of K (EPI==6 writes partials).
template<int EPI>
__global__ __launch_bounds__(256) void gemm_k(
    const _Float16* __restrict__ A, const _Float16* __restrict__ W,
    int N, int K, int lda, int kChunk, EpiP ep)
{
    __shared__ _Float16 As[128 * 32];   // 8 KB, slot-swizzled
    __shared__ _Float16 Bs[128 * 32];
    const int tid  = threadIdx.x;
    const int lane = tid & 63;
    const int wave = tid >> 6;
    const int wm = (wave >> 1) * 64;
    const int wn = (wave & 1) * 64;
    const int lr = lane & 15;
    const int lq = lane >> 4;
    const long tm = (long)blockIdx.y * 128;
    const int  tn = blockIdx.x * 128;

    // staging: slot p = wave*128 + c*64 + lane (c = 0,1)
    // slot(r,cc) = r*4 + ((cc + (r>>1)) & 3)  ->  cc = ((p&3) - ((r>>1)&3)) & 3
    const int p0 = wave * 128 + lane;
    const int r0 = p0 >> 2, c0 = ((p0 & 3) - ((r0 >> 1) & 3)) & 3;
    const int p1 = p0 + 64;
    const int r1 = p1 >> 2, c1 = ((p1 & 3) - ((r1 >> 1) & 3)) & 3;
    const _Float16* lA0 = &As[wave * 1024];
    const _Float16* lA1 = &As[wave * 1024 + 512];
    const _Float16* lB0 = &Bs[wave * 1024];
    const _Float16* lB1 = &Bs[wave * 1024 + 512];

    const int kBeg = blockIdx.z * kChunk;
    const _Float16* a0 = A + (tm + r0) * (long)lda + kBeg + c0 * 8;
    const _Float16* a1 = A + (tm + r1) * (long)lda + kBeg + c1 * 8;
    const _Float16* w0 = W + (long)min(tn + r0, N - 1) * K + kBeg + c0 * 8;
    const _Float16* w1 = W + (long)min(tn + r1, N - 1) * K + kBeg + c1 * 8;

    floatx4 acc[4][4];
#pragma unroll
    for (int i = 0; i < 4; i++)
#pragma unroll
        for (int j = 0; j < 4; j++) acc[i][j] = (floatx4)0.0f;

    for (int it = 0; it < kChunk / 32; it++) {
        gload_lds16(a0, lA0);
        gload_lds16(a1, lA1);
        gload_lds16(w0, lB0);
        gload_lds16(w1, lB1);
        a0 += 32; a1 += 32; w0 += 32; w1 += 32;
        __syncthreads();

        half8 af[4], bf[4];
#pragma unroll
        for (int i = 0; i < 4; i++) {
            int row = wm + i * 16 + lr;
            int slot = row * 4 + ((lq + (row >> 1)) & 3);
            af[i] = *(const half8*)&As[slot * 8];
        }
#pragma unroll
        for (int j = 0; j < 4; j++) {
            int row = wn + j * 16 + lr;
            int slot = row * 4 + ((lq + (row >> 1)) & 3);
            bf[j] = *(const half8*)&Bs[slot * 8];
        }
#pragma unroll
        for (int i = 0; i < 4; i++)
#pragma unroll
            for (int j = 0; j < 4; j++)
                acc[i][j] = __builtin_amdgcn_mfma_f32_16x16x32_f16(af[i], bf[j], acc[i][j], 0, 0, 0);
        __syncthreads();
    }

    // ---- epilogue ----
#pragma unroll
    for (int i = 0; i < 4; i++) {
#pragma unroll
        for (int p = 0; p < 4; p++) {
            long m = tm + wm + i * 16 + lq * 4 + p;
#pragma unroll
            for (int j = 0; j < 4; j++) {
                int n = tn + wn + j * 16 + lr;
                if (n >= N) continue;
                float v = acc[i][j][p];
                if constexpr (EPI == 0) {            // input: +bias -> h32, h16
                    v += ep.bias[n];
                    ep.o32[m * DM + n] = v;
                    ep.o16[m * DM + n] = (_Float16)v;
                } else if constexpr (EPI == 1) {     // inproj: conv+silu -> xc ; silu -> zs
                    if (n < DI) {
                        float s = v * ep.cw[n * DC + 3] + ep.cb[n];
                        ep.o16[m * DI + n] = (_Float16)silu_f(s);
                    } else {
                        ep.o16b[m * DI + (n - DI)] = (_Float16)silu_f(v);
                    }
                } else if constexpr (EPI == 3) {     // dt: softplus, y = xc*(dt*BC+D)*zs
                    float dtv = v + ep.dtb[n];
                    dtv = (dtv > 20.0f) ? dtv : log1pf(__expf(dtv));
                    float y = (float)ep.xc[m * DI + n] * (dtv * ep.BC[m] + ep.Dp[n]) * (float)ep.zs[m * DI + n];
                    ep.o16[m * DI + n] = (_Float16)y;
                } else if constexpr (EPI == 4) {     // out GEMM -> lnin fp32
                    ep.o32[m * DM + n] = v;
                } else if constexpr (EPI == 5) {     // final: +bias -> d_out
                    ep.o32[m * OUT_DIM + n] = v + ep.bias[n];
                } else {                              // EPI 6: split-K partial (xproj, N=96)
                    ep.o32[((long)blockIdx.z * BATCH + m) * 96 + n] = v;
                }
            }
        }
    }
}

// reduce xproj split-K partials -> xdbl fp16 ; fold in BC[b] = Bm . Cm
__global__ __launch_bounds__(128) void xred_k(
    const float* __restrict__ part, _Float16* __restrict__ xdbl, float* __restrict__ BC)
{
    int b = blockIdx.x;
    int t = threadIdx.x;
    __shared__ float s[96];
    if (t < 96) {
        float v = 0.0f;
#pragma unroll
        for (int z = 0; z < 8; z++) v += part[((long)z * BATCH + b) * 96 + t];
        xdbl[(long)b * 96 + t] = (_Float16)v;
        s[t] = v;
    }
    __syncthreads();
    if (t == 0) {
        float acc = 0.0f;
#pragma unroll
        for (int n = 0; n < DS_N; n++) acc += s[DTR + n] * s[DTR + DS_N + n];
        BC[b] = acc;
    }
}

__global__ __launch_bounds__(256) void ln_k(
    const float* __restrict__ xin, const float* __restrict__ g, const float* __restrict__ b,
    float* __restrict__ h32, _Float16* __restrict__ h16)
{
    long row = blockIdx.x;
    const float* x = xin + row * DM;
    int t = threadIdx.x;
    float v[4];
    float s = 0.0f, ss = 0.0f;
#pragma unroll
    for (int i = 0; i < 4; i++) {
        v[i] = x[t + i * 256];
        s += v[i];
        ss += v[i] * v[i];
    }
#pragma unroll
    for (int o = 32; o > 0; o >>= 1) {
        s  += __shfl_down(s, o, 64);
        ss += __shfl_down(ss, o, 64);
    }
    __shared__ float rs[4], rss[4];
    int wv = t >> 6, ln = t & 63;
    if (ln == 0) { rs[wv] = s; rss[wv] = ss; }
    __syncthreads();
    if (t == 0) {
        float S  = rs[0] + rs[1] + rs[2] + rs[3];
        float SS = rss[0] + rss[1] + rss[2] + rss[3];
        float mu = S / (float)DM;
        float var = SS / (float)DM - mu * mu;
        rs[0]  = mu;
        rss[0] = rsqrtf(var + 1e-5f);
    }
    __syncthreads();
    float mu = rs[0], rstd = rss[0];
#pragma unroll
    for (int i = 0; i < 4; i++) {
        int c = t + i * 256;
        float hv = h32[row * DM + c] + (v[i] - mu) * rstd * g[c] + b[c];
        h32[row * DM + c] = hv;
        h16[row * DM + c] = (_Float16)hv;
    }
}

extern "C" void kernel_launch(void* const* d_in, const int* in_sizes, int n_in,
                              void* d_out, int out_size, void* d_ws, size_t ws_size,
                              hipStream_t stream) {
    const float* x         = (const float*)d_in[0];
    const float* inp_w     = (const float*)d_in[1];
    const float* inp_b     = (const float*)d_in[2];
    const float* in_proj_w = (const float*)d_in[3];
    const float* conv_w    = (const float*)d_in[4];
    const float* conv_b    = (const float*)d_in[5];
    const float* xproj_w   = (const float*)d_in[6];
    const float* dt_w      = (const float*)d_in[7];
    const float* dt_b      = (const float*)d_in[8];
    // d_in[9] = A_log : unused (Ls==1, h0==0)
    const float* D_param   = (const float*)d_in[10];
    const float* out_w     = (const float*)d_in[11];
    const float* ln_g      = (const float*)d_in[12];
    const float* ln_b      = (const float*)d_in[13];
    const float* outp_w    = (const float*)d_in[14];
    const float* outp_b    = (const float*)d_in[15];

    char* ws = (char*)d_ws;
    _Float16* wf   = (_Float16*)ws;                      // fp16 arena, 55.84 MB
    float*    h32  = (float*)   (ws + (56u  << 20));     // 16 MB residual fp32
    _Float16* h16  = (_Float16*)(ws + (72u  << 20));     //  8 MB
    _Float16* xc16 = (_Float16*)(ws + (80u  << 20));     // 16 MB (y16 in place)
    _Float16* zs16 = (_Float16*)(ws + (96u  << 20));     // 16 MB
    float*    lnin = (float*)   (ws + (96u  << 20));     // aliases zs16 (dead then)
    _Float16* xdbl = (_Float16*)(ws + (112u << 20));     // 768 KB
    float*    BC   = (float*)   (ws + (113u << 20));     // 16 KB
    float*    xpart= (float*)   (ws + (114u << 20));     // 12 MB split-K partials

    dim3 blk(256);
    EpiP ep;

    // weights + x -> fp16 arena (grid covers E_TOT exactly)
    cvt_k<<<dim3((unsigned)(E_TOT / (256 * 8))), blk, 0, stream>>>(
        x, inp_w, in_proj_w, xproj_w, dt_w, out_w, outp_w, wf);

    // input GEMM: h = x @ inp_w^T + b   (M=4096, N=1024, K=256)
    ep = EpiP{}; ep.bias = inp_b; ep.o32 = h32; ep.o16 = h16;
    gemm_k<0><<<dim3(DM / 128, BATCH / 128, 1), blk, 0, stream>>>(
        wf + E_X, wf + E_INPW, DM, IN_DIM, IN_DIM, IN_DIM, ep);

    for (int l = 0; l < NL; l++) {
        // inproj (N=4096, K=1024) fused conv+silu / silu
        ep = EpiP{}; ep.o16 = xc16; ep.o16b = zs16;
        ep.cw = conv_w + (size_t)l * DI * DC; ep.cb = conv_b + (size_t)l * DI;
        gemm_k<1><<<dim3(2 * DI / 128, BATCH / 128, 1), blk, 0, stream>>>(
            h16, wf + E_INPROJ + (size_t)l * 2 * DI * DM, 2 * DI, DM, DM, DM, ep);

        // xproj (N=96, K=2048) split-K=8 -> partials
        ep = EpiP{}; ep.o32 = xpart;
        gemm_k<6><<<dim3(1, BATCH / 128, 8), blk, 0, stream>>>(
            xc16, wf + E_XPROJ + (size_t)l * (DTR + 2 * DS_N) * DI,
            DTR + 2 * DS_N, DI, DI, DI / 8, ep);

        // reduce partials -> xdbl fp16, BC
        xred_k<<<dim3(BATCH), dim3(128), 0, stream>>>(xpart, xdbl, BC);

        // dt GEMM (N=2048, K=64) + scan-collapse epilogue -> y16 (in place)
        ep = EpiP{}; ep.o16 = xc16;
        ep.dtb = dt_b + (size_t)l * DI; ep.Dp = D_param + (size_t)l * DI;
        ep.BC = BC; ep.xc = xc16; ep.zs = zs16;
        gemm_k<3><<<dim3(DI / 128, BATCH / 128, 1), blk, 0, stream>>>(
            xdbl, wf + E_DTW + (size_t)l * DI * DTR, DI, DTR, 96, DTR, ep);

        // out GEMM (N=1024, K=2048) -> lnin
        ep = EpiP{}; ep.o32 = lnin;
        gemm_k<4><<<dim3(DM / 128, BATCH / 128, 1), blk, 0, stream>>>(
            xc16, wf + E_OUTW + (size_t)l * DM * DI, DM, DI, DI, DI, ep);

        // LayerNorm + residual
        ln_k<<<dim3(BATCH), blk, 0, stream>>>(
            lnin, ln_g + (size_t)l * DM, ln_b + (size_t)l * DM, h32, h16);
    }

    // final (N=128, K=1024) -> d_out
    ep = EpiP{}; ep.bias = outp_b; ep.o32 = (float*)d_out;
    gemm_k<5><<<dim3(1, BATCH / 128, 1), blk, 0, stream>>>(
        h16, wf + E_OUTPW, OUT_DIM, DM, DM, DM, ep);
}

// Round 3
// 1241.432 us; speedup vs baseline: 1.2834x; 1.1810x over previous
//
#include <hip/hip_runtime.h>
#include <hip/hip_bf16.h>
#include <hip/hip_fp16.h>

#define NL 4
#define DM 1024
#define DI 2048
#define DS_N 16
#define DC 4
#define DTR 64
#define IN_DIM 256
#define OUT_DIM 128
#define BATCH 4096

typedef _Float16 half8 __attribute__((ext_vector_type(8)));
typedef _Float16 half4 __attribute__((ext_vector_type(4)));
typedef float floatx4 __attribute__((ext_vector_type(4)));

// element offsets into the fp16 arena (x + all weights, concatenated)
#define E_X      0L
#define E_INPW   (E_X + (long)BATCH * IN_DIM)
#define E_INPROJ (E_INPW + (long)DM * IN_DIM)
#define E_XPROJ  (E_INPROJ + (long)NL * 2 * DI * DM)
#define E_DTW    (E_XPROJ + (long)NL * (DTR + 2 * DS_N) * DI)
#define E_OUTW   (E_DTW + (long)NL * DI * DTR)
#define E_OUTPW  (E_OUTW + (long)NL * DM * DI)
#define E_TOT    (E_OUTPW + (long)OUT_DIM * DM)          // 27918336

__device__ __forceinline__ float silu_f(float x) {
    return x / (1.0f + __expf(-x));
}

__device__ __forceinline__ void gload_lds16(const _Float16* g, const _Float16* l) {
    __builtin_amdgcn_global_load_lds(
        (const __attribute__((address_space(1))) void*)(uintptr_t)g,
        (__attribute__((address_space(3))) void*)(uintptr_t)l,
        16, 0, 0);
}

// fp32 -> fp16 arena conversion (x + all weights). 8 elems/thread.
__global__ __launch_bounds__(256) void cvt_k(
    const float* __restrict__ x, const float* __restrict__ inp_w,
    const float* __restrict__ in_proj_w, const float* __restrict__ xproj_w,
    const float* __restrict__ dt_w, const float* __restrict__ out_w,
    const float* __restrict__ outp_w, _Float16* __restrict__ dst)
{
    long i = ((long)blockIdx.x * 256 + threadIdx.x) * 8;
    const float* s;
    if      (i < E_INPW)   s = x         + (i - E_X);
    else if (i < E_INPROJ) s = inp_w     + (i - E_INPW);
    else if (i < E_XPROJ)  s = in_proj_w + (i - E_INPROJ);
    else if (i < E_DTW)    s = xproj_w   + (i - E_XPROJ);
    else if (i < E_OUTW)   s = dt_w      + (i - E_DTW);
    else if (i < E_OUTPW)  s = out_w     + (i - E_OUTW);
    else                   s = outp_w    + (i - E_OUTPW);
    float4 a = *(const float4*)s;
    float4 b = *(const float4*)(s + 4);
    half8 h;
    h[0]=(_Float16)a.x; h[1]=(_Float16)a.y; h[2]=(_Float16)a.z; h[3]=(_Float16)a.w;
    h[4]=(_Float16)b.x; h[5]=(_Float16)b.y; h[6]=(_Float16)b.z; h[7]=(_Float16)b.w;
    *(half8*)(dst + i) = h;
}

struct EpiP {
    float* o32;
    _Float16* o16;
    _Float16* o16b;
    const float* bias;
    const float* cw;
    const float* cb;
    const float* dtb;
    const float* Dp;
    const float* BC;
    const _Float16* xc;
    const _Float16* zs;
};

// C[M x N] = A[M x K(lda)] * W[N x K]^T, both fp16. Tile 128x128, BK=32,
// 4 waves x (4x4) 16x16x32 MFMAs. global_load_lds(16B) staging, XOR chunk
// swizzle. EPI 1/3/4: vectorized epilogue (LDS transpose -> half8 stores).
template<int EPI>
__global__ __launch_bounds__(256) void gemm_k(
    const _Float16* __restrict__ A, const _Float16* __restrict__ W,
    int N, int K, int lda, int kChunk, EpiP ep)
{
    __shared__ __align__(16) char smem[36864];   // K-loop: 16 KB; epilogue slabs: 36 KB
    _Float16* As = (_Float16*)smem;
    _Float16* Bs = (_Float16*)(smem + 8192);
    const int tid  = threadIdx.x;
    const int lane = tid & 63;
    const int wave = tid >> 6;
    const int wm = (wave >> 1) * 64;
    const int wn = (wave & 1) * 64;
    const int lr = lane & 15;
    const int lq = lane >> 4;
    const long tm = (long)blockIdx.y * 128;
    const int  tn = blockIdx.x * 128;

    // staging: slot p = wave*128 + c*64 + lane ; slot(r,cc) = r*4 + ((cc + (r>>1)) & 3)
    const int p0 = wave * 128 + lane;
    const int r0 = p0 >> 2, c0 = ((p0 & 3) - ((r0 >> 1) & 3)) & 3;
    const int p1 = p0 + 64;
    const int r1 = p1 >> 2, c1 = ((p1 & 3) - ((r1 >> 1) & 3)) & 3;
    const _Float16* lA0 = &As[wave * 1024];
    const _Float16* lA1 = &As[wave * 1024 + 512];
    const _Float16* lB0 = &Bs[wave * 1024];
    const _Float16* lB1 = &Bs[wave * 1024 + 512];

    const int kBeg = blockIdx.z * kChunk;
    const _Float16* a0 = A + (tm + r0) * (long)lda + kBeg + c0 * 8;
    const _Float16* a1 = A + (tm + r1) * (long)lda + kBeg + c1 * 8;
    const _Float16* w0 = W + (long)min(tn + r0, N - 1) * K + kBeg + c0 * 8;
    const _Float16* w1 = W + (long)min(tn + r1, N - 1) * K + kBeg + c1 * 8;

    floatx4 acc[4][4];
#pragma unroll
    for (int i = 0; i < 4; i++)
#pragma unroll
        for (int j = 0; j < 4; j++) acc[i][j] = (floatx4)0.0f;

    for (int it = 0; it < kChunk / 32; it++) {
        gload_lds16(a0, lA0);
        gload_lds16(a1, lA1);
        gload_lds16(w0, lB0);
        gload_lds16(w1, lB1);
        a0 += 32; a1 += 32; w0 += 32; w1 += 32;
        __syncthreads();

        half8 af[4], bf[4];
#pragma unroll
        for (int i = 0; i < 4; i++) {
            int row = wm + i * 16 + lr;
            int slot = row * 4 + ((lq + (row >> 1)) & 3);
            af[i] = *(const half8*)&As[slot * 8];
        }
#pragma unroll
        for (int j = 0; j < 4; j++) {
            int row = wn + j * 16 + lr;
            int slot = row * 4 + ((lq + (row >> 1)) & 3);
            bf[j] = *(const half8*)&Bs[slot * 8];
        }
#pragma unroll
        for (int i = 0; i < 4; i++)
#pragma unroll
            for (int j = 0; j < 4; j++)
                acc[i][j] = __builtin_amdgcn_mfma_f32_16x16x32_f16(af[i], bf[j], acc[i][j], 0, 0, 0);
        __syncthreads();
    }

    if constexpr (EPI == 1 || EPI == 3 || EPI == 4) {
        // ---- vectorized epilogue: wave-private 64x72 LDS transpose ----
        _Float16* slab = (_Float16*)(smem + wave * 9216);
#pragma unroll
        for (int i = 0; i < 4; i++)
#pragma unroll
            for (int j = 0; j < 4; j++)
#pragma unroll
                for (int p = 0; p < 4; p++)
                    slab[(i * 16 + lq * 4 + p) * 72 + j * 16 + lr] = (_Float16)acc[i][j][p];
        long g = tm + wm + lane;       // this lane's global row
        const int cb0 = tn + wn;       // col base (64 cols per lane)
        float bc;
        if constexpr (EPI == 3) bc = ep.BC[g];
#pragma unroll
        for (int c = 0; c < 8; c++) {
            half8 hv = *(const half8*)&slab[lane * 72 + c * 8];
            int n0 = cb0 + c * 8;
            if constexpr (EPI == 1) {
                half8 o;
                if (cb0 < DI) {                    // xc side (block-uniform)
#pragma unroll
                    for (int k = 0; k < 8; k++) {
                        float s = (float)hv[k] * ep.cw[(n0 + k) * DC + 3] + ep.cb[n0 + k];
                        o[k] = (_Float16)silu_f(s);
                    }
                    *(half8*)&ep.o16[g * DI + n0] = o;
                } else {                           // z side
#pragma unroll
                    for (int k = 0; k < 8; k++) o[k] = (_Float16)silu_f((float)hv[k]);
                    *(half8*)&ep.o16b[g * DI + (n0 - DI)] = o;
                }
            } else if constexpr (EPI == 3) {
                half8 xcv = *(const half8*)&ep.xc[g * DI + n0];
                half8 zsv = *(const half8*)&ep.zs[g * DI + n0];
                half8 o;
#pragma unroll
                for (int k = 0; k < 8; k++) {
                    float dtv = (float)hv[k] + ep.dtb[n0 + k];
                    dtv = (dtv > 20.0f) ? dtv : log1pf(__expf(dtv));
                    float y = (float)xcv[k] * (dtv * bc + ep.Dp[n0 + k]) * (float)zsv[k];
                    o[k] = (_Float16)y;
                }
                *(half8*)&ep.o16[g * DI + n0] = o;
            } else {                                // EPI 4: lnin fp16
                *(half8*)&ep.o16[g * DM + n0] = hv;
            }
        }
    } else {
        // ---- scalar epilogue (small kernels: EPI 0, 5, 6) ----
#pragma unroll
        for (int i = 0; i < 4; i++) {
#pragma unroll
            for (int p = 0; p < 4; p++) {
                long m = tm + wm + i * 16 + lq * 4 + p;
#pragma unroll
                for (int j = 0; j < 4; j++) {
                    int n = tn + wn + j * 16 + lr;
                    if (n >= N) continue;
                    float v = acc[i][j][p];
                    if constexpr (EPI == 0) {            // input: +bias -> h32, h16
                        v += ep.bias[n];
                        ep.o32[m * DM + n] = v;
                        ep.o16[m * DM + n] = (_Float16)v;
                    } else if constexpr (EPI == 5) {     // final: +bias -> d_out
                        ep.o32[m * OUT_DIM + n] = v + ep.bias[n];
                    } else {                              // EPI 6: split-K partials (xproj)
                        ep.o32[((long)blockIdx.z * BATCH + m) * 96 + n] = v;
                    }
                }
            }
        }
    }
}

// reduce xproj split-K partials -> xdbl fp16 (float4-vectorized)
__global__ __launch_bounds__(256) void xred_k(
    const float* __restrict__ part, _Float16* __restrict__ xdbl)
{
    long i = ((long)blockIdx.x * 256 + threadIdx.x) * 4;   // flat over BATCH*96
    float4 s = make_float4(0.f, 0.f, 0.f, 0.f);
#pragma unroll
    for (int z = 0; z < 8; z++) {
        float4 v = *(const float4*)&part[(long)z * BATCH * 96 + i];
        s.x += v.x; s.y += v.y; s.z += v.z; s.w += v.w;
    }
    half4 h;
    h[0] = (_Float16)s.x; h[1] = (_Float16)s.y; h[2] = (_Float16)s.z; h[3] = (_Float16)s.w;
    *(half4*)&xdbl[i] = h;
}

// BC[b] = Bm . Cm  (cols 64..79 dot cols 80..95 of xdbl)
__global__ __launch_bounds__(256) void bc_k(
    const _Float16* __restrict__ xdbl, float* __restrict__ BC)
{
    int b = blockIdx.x * 256 + threadIdx.x;
    const half8* p = (const half8*)(xdbl + (long)b * 96 + DTR);
    half8 b0 = p[0], b1 = p[1], c0 = p[2], c1 = p[3];
    float s = 0.0f;
#pragma unroll
    for (int k = 0; k < 8; k++)
        s += (float)b0[k] * (float)c0[k] + (float)b1[k] * (float)c1[k];
    BC[b] = s;
}

__global__ __launch_bounds__(256) void ln_k(
    const _Float16* __restrict__ xin, const float* __restrict__ g, const float* __restrict__ b,
    float* __restrict__ h32, _Float16* __restrict__ h16)
{
    long row = blockIdx.x;
    const _Float16* x = xin + row * DM;
    int t = threadIdx.x;
    float v[4];
    float s = 0.0f, ss = 0.0f;
#pragma unroll
    for (int i = 0; i < 4; i++) {
        v[i] = (float)x[t + i * 256];
        s += v[i];
        ss += v[i] * v[i];
    }
#pragma unroll
    for (int o = 32; o > 0; o >>= 1) {
        s  += __shfl_down(s, o, 64);
        ss += __shfl_down(ss, o, 64);
    }
    __shared__ float rs[4], rss[4];
    int wv = t >> 6, ln = t & 63;
    if (ln == 0) { rs[wv] = s; rss[wv] = ss; }
    __syncthreads();
    if (t == 0) {
        float S  = rs[0] + rs[1] + rs[2] + rs[3];
        float SS = rss[0] + rss[1] + rss[2] + rss[3];
        float mu = S / (float)DM;
        float var = SS / (float)DM - mu * mu;
        rs[0]  = mu;
        rss[0] = rsqrtf(var + 1e-5f);
    }
    __syncthreads();
    float mu = rs[0], rstd = rss[0];
#pragma unroll
    for (int i = 0; i < 4; i++) {
        int c = t + i * 256;
        float hv = h32[row * DM + c] + (v[i] - mu) * rstd * g[c] + b[c];
        h32[row * DM + c] = hv;
        h16[row * DM + c] = (_Float16)hv;
    }
}

extern "C" void kernel_launch(void* const* d_in, const int* in_sizes, int n_in,
                              void* d_out, int out_size, void* d_ws, size_t ws_size,
                              hipStream_t stream) {
    const float* x         = (const float*)d_in[0];
    const float* inp_w     = (const float*)d_in[1];
    const float* inp_b     = (const float*)d_in[2];
    const float* in_proj_w = (const float*)d_in[3];
    const float* conv_w    = (const float*)d_in[4];
    const float* conv_b    = (const float*)d_in[5];
    const float* xproj_w   = (const float*)d_in[6];
    const float* dt_w      = (const float*)d_in[7];
    const float* dt_b      = (const float*)d_in[8];
    // d_in[9] = A_log : unused (Ls==1, h0==0)
    const float* D_param   = (const float*)d_in[10];
    const float* out_w     = (const float*)d_in[11];
    const float* ln_g      = (const float*)d_in[12];
    const float* ln_b      = (const float*)d_in[13];
    const float* outp_w    = (const float*)d_in[14];
    const float* outp_b    = (const float*)d_in[15];

    char* ws = (char*)d_ws;
    _Float16* wf    = (_Float16*)ws;                      // fp16 arena, 55.84 MB
    float*    h32   = (float*)   (ws + (56u  << 20));     // 16 MB residual fp32
    _Float16* h16   = (_Float16*)(ws + (72u  << 20));     //  8 MB
    _Float16* xc16  = (_Float16*)(ws + (80u  << 20));     // 16 MB (y16 in place)
    _Float16* zs16  = (_Float16*)(ws + (96u  << 20));     // 16 MB
    _Float16* lnin16= (_Float16*)(ws + (96u  << 20));     // 8 MB, aliases zs16 (dead)
    _Float16* xdbl  = (_Float16*)(ws + (112u << 20));     // 768 KB
    float*    BC    = (float*)   (ws + (113u << 20));     // 16 KB
    float*    xpart = (float*)   (ws + (114u << 20));     // 12.6 MB split-K partials

    dim3 blk(256);
    EpiP ep;

    cvt_k<<<dim3((unsigned)(E_TOT / (256 * 8))), blk, 0, stream>>>(
        x, inp_w, in_proj_w, xproj_w, dt_w, out_w, outp_w, wf);

    // input GEMM: h = x @ inp_w^T + b   (N=1024, K=256)
    ep = EpiP{}; ep.bias = inp_b; ep.o32 = h32; ep.o16 = h16;
    gemm_k<0><<<dim3(DM / 128, BATCH / 128, 1), blk, 0, stream>>>(
        wf + E_X, wf + E_INPW, DM, IN_DIM, IN_DIM, IN_DIM, ep);

    for (int l = 0; l < NL; l++) {
        // inproj (N=4096, K=1024): fused conv+silu -> xc16, silu -> zs16
        ep = EpiP{}; ep.o16 = xc16; ep.o16b = zs16;
        ep.cw = conv_w + (size_t)l * DI * DC; ep.cb = conv_b + (size_t)l * DI;
        gemm_k<1><<<dim3(2 * DI / 128, BATCH / 128, 1), blk, 0, stream>>>(
            h16, wf + E_INPROJ + (size_t)l * 2 * DI * DM, 2 * DI, DM, DM, DM, ep);

        // xproj (N=96, K=2048) split-K=8 -> partials
        ep = EpiP{}; ep.o32 = xpart;
        gemm_k<6><<<dim3(1, BATCH / 128, 8), blk, 0, stream>>>(
            xc16, wf + E_XPROJ + (size_t)l * (DTR + 2 * DS_N) * DI,
            DTR + 2 * DS_N, DI, DI, DI / 8, ep);

        xred_k<<<dim3(BATCH * 96 / 4 / 256), blk, 0, stream>>>(xpart, xdbl);
        bc_k<<<dim3(BATCH / 256), blk, 0, stream>>>(xdbl, BC);

        // dt GEMM (N=2048, K=64) + vectorized scan-collapse -> y16 (in place)
        ep = EpiP{}; ep.o16 = xc16;
        ep.dtb = dt_b + (size_t)l * DI; ep.Dp = D_param + (size_t)l * DI;
        ep.BC = BC; ep.xc = xc16; ep.zs = zs16;
        gemm_k<3><<<dim3(DI / 128, BATCH / 128, 1), blk, 0, stream>>>(
            xdbl, wf + E_DTW + (size_t)l * DI * DTR, DI, DTR, 96, DTR, ep);

        // out GEMM (N=1024, K=2048) -> lnin16
        ep = EpiP{}; ep.o16 = lnin16;
        gemm_k<4><<<dim3(DM / 128, BATCH / 128, 1), blk, 0, stream>>>(
            xc16, wf + E_OUTW + (size_t)l * DM * DI, DM, DI, DI, DI, ep);

        // LayerNorm + residual
        ln_k<<<dim3(BATCH), blk, 0, stream>>>(
            lnin16, ln_g + (size_t)l * DM, ln_b + (size_t)l * DM, h32, h16);
    }

    // final (N=128, K=1024) -> d_out
    ep = EpiP{}; ep.bias = outp_b; ep.o32 = (float*)d_out;
    gemm_k<5><<<dim3(1, BATCH / 128, 1), blk, 0, stream>>>(
        h16, wf + E_OUTPW, OUT_DIM, DM, DM, DM, ep);
}

// Round 4
// 865.758 us; speedup vs baseline: 1.8404x; 1.4339x over previous
//
#include <hip/hip_runtime.h>
#include <hip/hip_bf16.h>
#include <hip/hip_fp16.h>

#define NL 4
#define DM 1024
#define DI 2048
#define DS_N 16
#define DC 4
#define DTR 64
#define IN_DIM 256
#define OUT_DIM 128
#define BATCH 4096

typedef _Float16 half8 __attribute__((ext_vector_type(8)));
typedef _Float16 half4 __attribute__((ext_vector_type(4)));
typedef float floatx4 __attribute__((ext_vector_type(4)));

// element offsets into the fp16 arena (x + all weights, concatenated)
#define E_X      0L
#define E_INPW   (E_X + (long)BATCH * IN_DIM)
#define E_INPROJ (E_INPW + (long)DM * IN_DIM)
#define E_XPROJ  (E_INPROJ + (long)NL * 2 * DI * DM)
#define E_DTW    (E_XPROJ + (long)NL * (DTR + 2 * DS_N) * DI)
#define E_OUTW   (E_DTW + (long)NL * DI * DTR)
#define E_OUTPW  (E_OUTW + (long)NL * DM * DI)
#define E_TOT    (E_OUTPW + (long)OUT_DIM * DM)          // 27918336

__device__ __forceinline__ float silu_f(float x) {
    return x / (1.0f + __expf(-x));
}

__device__ __forceinline__ void gload_lds16(const _Float16* g, const _Float16* l) {
    __builtin_amdgcn_global_load_lds(
        (const __attribute__((address_space(1))) void*)(uintptr_t)g,
        (__attribute__((address_space(3))) void*)(uintptr_t)l,
        16, 0, 0);
}

// fp32 -> fp16 arena conversion (x + all weights). 8 elems/thread.
__global__ __launch_bounds__(256) void cvt_k(
    const float* __restrict__ x, const float* __restrict__ inp_w,
    const float* __restrict__ in_proj_w, const float* __restrict__ xproj_w,
    const float* __restrict__ dt_w, const float* __restrict__ out_w,
    const float* __restrict__ outp_w, _Float16* __restrict__ dst)
{
    long i = ((long)blockIdx.x * 256 + threadIdx.x) * 8;
    const float* s;
    if      (i < E_INPW)   s = x         + (i - E_X);
    else if (i < E_INPROJ) s = inp_w     + (i - E_INPW);
    else if (i < E_XPROJ)  s = in_proj_w + (i - E_INPROJ);
    else if (i < E_DTW)    s = xproj_w   + (i - E_XPROJ);
    else if (i < E_OUTW)   s = dt_w      + (i - E_DTW);
    else if (i < E_OUTPW)  s = out_w     + (i - E_OUTW);
    else                   s = outp_w    + (i - E_OUTPW);
    float4 a = *(const float4*)s;
    float4 b = *(const float4*)(s + 4);
    half8 h;
    h[0]=(_Float16)a.x; h[1]=(_Float16)a.y; h[2]=(_Float16)a.z; h[3]=(_Float16)a.w;
    h[4]=(_Float16)b.x; h[5]=(_Float16)b.y; h[6]=(_Float16)b.z; h[7]=(_Float16)b.w;
    *(half8*)(dst + i) = h;
}

struct EpiP {
    float* o32;
    _Float16* o16;
    _Float16* o16b;
    const float* bias;
    const float* cw;
    const float* cb;
    const float* dtb;
    const float* Dp;
    const _Float16* xc;
    const _Float16* zs;
};

// C[M x N] = A[M x K(lda)] * W[N x K]^T, both fp16. Tile 128x128, BK=32,
// 4 waves x (4x4) 16x16x32 MFMAs, global_load_lds(16B) staging.
// Epilogue (all EPI but 5): LDS slab transpose, then line-contiguous stores:
// lane = (row-sub = lane>>3, col-chunk = lane&7); each store instruction
// covers 8 full 128-B cache lines (no partial-line scatter).
template<int EPI>
__global__ __launch_bounds__(256) void gemm_k(
    const _Float16* __restrict__ A, const _Float16* __restrict__ W,
    int N, int K, int lda, int kChunk, EpiP ep)
{
    __shared__ __align__(16) char smem[36864];   // K-loop: 16 KB; epilogue: 4x9 KB slabs
    _Float16* As = (_Float16*)smem;
    _Float16* Bs = (_Float16*)(smem + 8192);
    const int tid  = threadIdx.x;
    const int lane = tid & 63;
    const int wave = tid >> 6;
    const int wm = (wave >> 1) * 64;
    const int wn = (wave & 1) * 64;
    const int lr = lane & 15;
    const int lq = lane >> 4;
    const long tm = (long)blockIdx.y * 128;
    const int  tn = blockIdx.x * 128;

    // staging: slot p = wave*128 + c*64 + lane ; slot(r,cc) = r*4 + ((cc + (r>>1)) & 3)
    const int p0 = wave * 128 + lane;
    const int r0 = p0 >> 2, c0 = ((p0 & 3) - ((r0 >> 1) & 3)) & 3;
    const int p1 = p0 + 64;
    const int r1 = p1 >> 2, c1 = ((p1 & 3) - ((r1 >> 1) & 3)) & 3;
    const _Float16* lA0 = &As[wave * 1024];
    const _Float16* lA1 = &As[wave * 1024 + 512];
    const _Float16* lB0 = &Bs[wave * 1024];
    const _Float16* lB1 = &Bs[wave * 1024 + 512];

    const int kBeg = blockIdx.z * kChunk;
    const _Float16* a0 = A + (tm + r0) * (long)lda + kBeg + c0 * 8;
    const _Float16* a1 = A + (tm + r1) * (long)lda + kBeg + c1 * 8;
    const _Float16* w0 = W + (long)min(tn + r0, N - 1) * K + kBeg + c0 * 8;
    const _Float16* w1 = W + (long)min(tn + r1, N - 1) * K + kBeg + c1 * 8;

    floatx4 acc[4][4];
#pragma unroll
    for (int i = 0; i < 4; i++)
#pragma unroll
        for (int j = 0; j < 4; j++) acc[i][j] = (floatx4)0.0f;

    for (int it = 0; it < kChunk / 32; it++) {
        gload_lds16(a0, lA0);
        gload_lds16(a1, lA1);
        gload_lds16(w0, lB0);
        gload_lds16(w1, lB1);
        a0 += 32; a1 += 32; w0 += 32; w1 += 32;
        __syncthreads();

        half8 af[4], bf[4];
#pragma unroll
        for (int i = 0; i < 4; i++) {
            int row = wm + i * 16 + lr;
            int slot = row * 4 + ((lq + (row >> 1)) & 3);
            af[i] = *(const half8*)&As[slot * 8];
        }
#pragma unroll
        for (int j = 0; j < 4; j++) {
            int row = wn + j * 16 + lr;
            int slot = row * 4 + ((lq + (row >> 1)) & 3);
            bf[j] = *(const half8*)&Bs[slot * 8];
        }
#pragma unroll
        for (int i = 0; i < 4; i++)
#pragma unroll
            for (int j = 0; j < 4; j++)
                acc[i][j] = __builtin_amdgcn_mfma_f32_16x16x32_f16(af[i], bf[j], acc[i][j], 0, 0, 0);
        __syncthreads();
    }

    if constexpr (EPI != 5) {
        // ---- line-contiguous epilogue via wave-private 64x72 LDS slab ----
        _Float16* slab = (_Float16*)(smem + wave * 9216);
#pragma unroll
        for (int i = 0; i < 4; i++)
#pragma unroll
            for (int j = 0; j < 4; j++)
#pragma unroll
                for (int p = 0; p < 4; p++)
                    slab[(i * 16 + lq * 4 + p) * 72 + j * 16 + lr] = (_Float16)acc[i][j][p];

        const int rsub = lane >> 3;       // row sub-index 0..7
        const int cch  = lane & 7;        // col chunk 0..7
        const int cb0  = tn + wn;
        const int n0   = cb0 + cch * 8;   // this lane's 8 columns (fixed)
        const long g0  = tm + wm;

        // per-lane channel-param preloads
        float bv[8], cwv[8], dtbv[8], dpv[8];
        if constexpr (EPI == 0) {
            float4 q0 = *(const float4*)&ep.bias[n0];
            float4 q1 = *(const float4*)&ep.bias[n0 + 4];
            bv[0]=q0.x; bv[1]=q0.y; bv[2]=q0.z; bv[3]=q0.w;
            bv[4]=q1.x; bv[5]=q1.y; bv[6]=q1.z; bv[7]=q1.w;
        }
        if constexpr (EPI == 1) {
            if (cb0 < DI) {
#pragma unroll
                for (int k = 0; k < 8; k++) cwv[k] = ep.cw[(n0 + k) * DC + 3];
                float4 q0 = *(const float4*)&ep.cb[n0];
                float4 q1 = *(const float4*)&ep.cb[n0 + 4];
                bv[0]=q0.x; bv[1]=q0.y; bv[2]=q0.z; bv[3]=q0.w;
                bv[4]=q1.x; bv[5]=q1.y; bv[6]=q1.z; bv[7]=q1.w;
            }
        }
        float bcv;
        if constexpr (EPI == 3) {
            float4 q0 = *(const float4*)&ep.dtb[n0];
            float4 q1 = *(const float4*)&ep.dtb[n0 + 4];
            dtbv[0]=q0.x; dtbv[1]=q0.y; dtbv[2]=q0.z; dtbv[3]=q0.w;
            dtbv[4]=q1.x; dtbv[5]=q1.y; dtbv[6]=q1.z; dtbv[7]=q1.w;
            float4 p0v = *(const float4*)&ep.Dp[n0];
            float4 p1v = *(const float4*)&ep.Dp[n0 + 4];
            dpv[0]=p0v.x; dpv[1]=p0v.y; dpv[2]=p0v.z; dpv[3]=p0v.w;
            dpv[4]=p1v.x; dpv[5]=p1v.y; dpv[6]=p1v.z; dpv[7]=p1v.w;
            // BC for this lane's row (g0+lane): Bm.Cm from xdbl (= A, lda 96)
            const half8* pp = (const half8*)(A + (g0 + lane) * 96 + DTR);
            half8 b0 = pp[0], b1 = pp[1], c0v = pp[2], c1v = pp[3];
            float s = 0.0f;
#pragma unroll
            for (int k = 0; k < 8; k++)
                s += (float)b0[k] * (float)c0v[k] + (float)b1[k] * (float)c1v[k];
            bcv = s;
        }

#pragma unroll
        for (int r = 0; r < 8; r++) {
            long g = g0 + r * 8 + rsub;
            half8 hv = *(const half8*)&slab[(r * 8 + rsub) * 72 + cch * 8];
            if constexpr (EPI == 0) {          // input: +bias -> h32 + h16
                float4 f0, f1; half8 o;
#pragma unroll
                for (int k = 0; k < 4; k++) {
                    float v = (float)hv[k] + bv[k];
                    (&f0.x)[k] = v; o[k] = (_Float16)v;
                }
#pragma unroll
                for (int k = 0; k < 4; k++) {
                    float v = (float)hv[k + 4] + bv[k + 4];
                    (&f1.x)[k] = v; o[k + 4] = (_Float16)v;
                }
                *(float4*)&ep.o32[g * DM + n0]     = f0;
                *(float4*)&ep.o32[g * DM + n0 + 4] = f1;
                *(half8*)&ep.o16[g * DM + n0] = o;
            } else if constexpr (EPI == 1) {   // inproj: conv+silu / silu
                half8 o;
                if (cb0 < DI) {
#pragma unroll
                    for (int k = 0; k < 8; k++) {
                        float s = (float)hv[k] * cwv[k] + bv[k];
                        o[k] = (_Float16)silu_f(s);
                    }
                    *(half8*)&ep.o16[g * DI + n0] = o;
                } else {
#pragma unroll
                    for (int k = 0; k < 8; k++) o[k] = (_Float16)silu_f((float)hv[k]);
                    *(half8*)&ep.o16b[g * DI + (n0 - DI)] = o;
                }
            } else if constexpr (EPI == 3) {   // dt: softplus, y = xc*(dt*BC+D)*zs
                float bc = __shfl(bcv, r * 8 + rsub, 64);
                half8 xcv = *(const half8*)&ep.xc[g * DI + n0];
                half8 zsv = *(const half8*)&ep.zs[g * DI + n0];
                half8 o;
#pragma unroll
                for (int k = 0; k < 8; k++) {
                    float dtv = (float)hv[k] + dtbv[k];
                    dtv = (dtv > 20.0f) ? dtv : log1pf(__expf(dtv));
                    float y = (float)xcv[k] * (dtv * bc + dpv[k]) * (float)zsv[k];
                    o[k] = (_Float16)y;
                }
                *(half8*)&ep.o16[g * DI + n0] = o;
            } else if constexpr (EPI == 4) {   // out -> lnin fp16
                *(half8*)&ep.o16[g * DM + n0] = hv;
            } else {                            // EPI 6: xproj split-K fp16 partials
                if (n0 < 96)
                    *(half8*)&ep.o16[((long)blockIdx.z * BATCH + g) * 96 + n0] = hv;
            }
        }
    } else {
        // ---- EPI 5 (final, N=128): scalar epilogue ----
#pragma unroll
        for (int i = 0; i < 4; i++) {
#pragma unroll
            for (int p = 0; p < 4; p++) {
                long m = tm + wm + i * 16 + lq * 4 + p;
#pragma unroll
                for (int j = 0; j < 4; j++) {
                    int n = tn + wn + j * 16 + lr;
                    if (n >= N) continue;
                    ep.o32[m * OUT_DIM + n] = acc[i][j][p] + ep.bias[n];
                }
            }
        }
    }
}

// reduce xproj split-K fp16 partials -> xdbl fp16
__global__ __launch_bounds__(256) void xred_k(
    const _Float16* __restrict__ part, _Float16* __restrict__ xdbl)
{
    long i = ((long)blockIdx.x * 256 + threadIdx.x) * 4;   // flat over BATCH*96
    float s0 = 0.f, s1 = 0.f, s2 = 0.f, s3 = 0.f;
#pragma unroll
    for (int z = 0; z < 8; z++) {
        half4 v = *(const half4*)&part[(long)z * BATCH * 96 + i];
        s0 += (float)v[0]; s1 += (float)v[1]; s2 += (float)v[2]; s3 += (float)v[3];
    }
    half4 h;
    h[0] = (_Float16)s0; h[1] = (_Float16)s1; h[2] = (_Float16)s2; h[3] = (_Float16)s3;
    *(half4*)&xdbl[i] = h;
}

__global__ __launch_bounds__(256) void ln_k(
    const _Float16* __restrict__ xin, const float* __restrict__ g, const float* __restrict__ b,
    float* __restrict__ h32, _Float16* __restrict__ h16)
{
    long row = blockIdx.x;
    const _Float16* x = xin + row * DM;
    int t = threadIdx.x;
    float v[4];
    float s = 0.0f, ss = 0.0f;
#pragma unroll
    for (int i = 0; i < 4; i++) {
        v[i] = (float)x[t + i * 256];
        s += v[i];
        ss += v[i] * v[i];
    }
#pragma unroll
    for (int o = 32; o > 0; o >>= 1) {
        s  += __shfl_down(s, o, 64);
        ss += __shfl_down(ss, o, 64);
    }
    __shared__ float rs[4], rss[4];
    int wv = t >> 6, ln = t & 63;
    if (ln == 0) { rs[wv] = s; rss[wv] = ss; }
    __syncthreads();
    if (t == 0) {
        float S  = rs[0] + rs[1] + rs[2] + rs[3];
        float SS = rss[0] + rss[1] + rss[2] + rss[3];
        float mu = S / (float)DM;
        float var = SS / (float)DM - mu * mu;
        rs[0]  = mu;
        rss[0] = rsqrtf(var + 1e-5f);
    }
    __syncthreads();
    float mu = rs[0], rstd = rss[0];
#pragma unroll
    for (int i = 0; i < 4; i++) {
        int c = t + i * 256;
        float hv = h32[row * DM + c] + (v[i] - mu) * rstd * g[c] + b[c];
        h32[row * DM + c] = hv;
        h16[row * DM + c] = (_Float16)hv;
    }
}

extern "C" void kernel_launch(void* const* d_in, const int* in_sizes, int n_in,
                              void* d_out, int out_size, void* d_ws, size_t ws_size,
                              hipStream_t stream) {
    const float* x         = (const float*)d_in[0];
    const float* inp_w     = (const float*)d_in[1];
    const float* inp_b     = (const float*)d_in[2];
    const float* in_proj_w = (const float*)d_in[3];
    const float* conv_w    = (const float*)d_in[4];
    const float* conv_b    = (const float*)d_in[5];
    const float* xproj_w   = (const float*)d_in[6];
    const float* dt_w      = (const float*)d_in[7];
    const float* dt_b      = (const float*)d_in[8];
    // d_in[9] = A_log : unused (Ls==1, h0==0)
    const float* D_param   = (const float*)d_in[10];
    const float* out_w     = (const float*)d_in[11];
    const float* ln_g      = (const float*)d_in[12];
    const float* ln_b      = (const float*)d_in[13];
    const float* outp_w    = (const float*)d_in[14];
    const float* outp_b    = (const float*)d_in[15];

    char* ws = (char*)d_ws;
    _Float16* wf    = (_Float16*)ws;                      // fp16 arena, 55.84 MB
    float*    h32   = (float*)   (ws + (56u  << 20));     // 16 MB residual fp32
    _Float16* h16   = (_Float16*)(ws + (72u  << 20));     //  8 MB
    _Float16* xc16  = (_Float16*)(ws + (80u  << 20));     // 16 MB (y16 in place)
    _Float16* zs16  = (_Float16*)(ws + (96u  << 20));     // 16 MB
    _Float16* lnin16= (_Float16*)(ws + (96u  << 20));     // 8 MB, aliases zs16 (dead)
    _Float16* xdbl  = (_Float16*)(ws + (112u << 20));     // 768 KB
    _Float16* xpart = (_Float16*)(ws + (114u << 20));     // 6.3 MB split-K fp16 partials

    dim3 blk(256);
    EpiP ep;

    cvt_k<<<dim3((unsigned)(E_TOT / (256 * 8))), blk, 0, stream>>>(
        x, inp_w, in_proj_w, xproj_w, dt_w, out_w, outp_w, wf);

    // input GEMM: h = x @ inp_w^T + b   (N=1024, K=256)
    ep = EpiP{}; ep.bias = inp_b; ep.o32 = h32; ep.o16 = h16;
    gemm_k<0><<<dim3(DM / 128, BATCH / 128, 1), blk, 0, stream>>>(
        wf + E_X, wf + E_INPW, DM, IN_DIM, IN_DIM, IN_DIM, ep);

    for (int l = 0; l < NL; l++) {
        // inproj (N=4096, K=1024): fused conv+silu -> xc16, silu -> zs16
        ep = EpiP{}; ep.o16 = xc16; ep.o16b = zs16;
        ep.cw = conv_w + (size_t)l * DI * DC; ep.cb = conv_b + (size_t)l * DI;
        gemm_k<1><<<dim3(2 * DI / 128, BATCH / 128, 1), blk, 0, stream>>>(
            h16, wf + E_INPROJ + (size_t)l * 2 * DI * DM, 2 * DI, DM, DM, DM, ep);

        // xproj (N=96, K=2048) split-K=8 -> fp16 partials
        ep = EpiP{}; ep.o16 = xpart;
        gemm_k<6><<<dim3(1, BATCH / 128, 8), blk, 0, stream>>>(
            xc16, wf + E_XPROJ + (size_t)l * (DTR + 2 * DS_N) * DI,
            DTR + 2 * DS_N, DI, DI, DI / 8, ep);

        xred_k<<<dim3(BATCH * 96 / 4 / 256), blk, 0, stream>>>(xpart, xdbl);

        // dt GEMM (N=2048, K=64) + scan-collapse (BC computed inline) -> y16
        ep = EpiP{}; ep.o16 = xc16;
        ep.dtb = dt_b + (size_t)l * DI; ep.Dp = D_param + (size_t)l * DI;
        ep.xc = xc16; ep.zs = zs16;
        gemm_k<3><<<dim3(DI / 128, BATCH / 128, 1), blk, 0, stream>>>(
            xdbl, wf + E_DTW + (size_t)l * DI * DTR, DI, DTR, 96, DTR, ep);

        // out GEMM (N=1024, K=2048) -> lnin16
        ep = EpiP{}; ep.o16 = lnin16;
        gemm_k<4><<<dim3(DM / 128, BATCH / 128, 1), blk, 0, stream>>>(
            xc16, wf + E_OUTW + (size_t)l * DM * DI, DM, DI, DI, DI, ep);

        // LayerNorm + residual
        ln_k<<<dim3(BATCH), blk, 0, stream>>>(
            lnin16, ln_g + (size_t)l * DM, ln_b + (size_t)l * DM, h32, h16);
    }

    // final (N=128, K=1024) -> d_out
    ep = EpiP{}; ep.bias = outp_b; ep.o32 = (float*)d_out;
    gemm_k<5><<<dim3(1, BATCH / 128, 1), blk, 0, stream>>>(
        h16, wf + E_OUTPW, OUT_DIM, DM, DM, DM, ep);
}

// Round 5
// 727.416 us; speedup vs baseline: 2.1904x; 1.1902x over previous
//
#include <hip/hip_runtime.h>
#include <hip/hip_bf16.h>
#include <hip/hip_fp16.h>

#define NL 4
#define DM 1024
#define DI 2048
#define DS_N 16
#define DC 4
#define DTR 64
#define IN_DIM 256
#define OUT_DIM 128
#define BATCH 4096

typedef _Float16 half8 __attribute__((ext_vector_type(8)));
typedef _Float16 half4 __attribute__((ext_vector_type(4)));
typedef float floatx4 __attribute__((ext_vector_type(4)));

// element offsets into the fp16 arena (x + all weights, concatenated)
#define E_X      0L
#define E_INPW   (E_X + (long)BATCH * IN_DIM)
#define E_INPROJ (E_INPW + (long)DM * IN_DIM)
#define E_XPROJ  (E_INPROJ + (long)NL * 2 * DI * DM)
#define E_DTW    (E_XPROJ + (long)NL * (DTR + 2 * DS_N) * DI)
#define E_OUTW   (E_DTW + (long)NL * DI * DTR)
#define E_OUTPW  (E_OUTW + (long)NL * DM * DI)
#define E_TOT    (E_OUTPW + (long)OUT_DIM * DM)          // 27918336

__device__ __forceinline__ float silu_f(float x) {
    return x / (1.0f + __expf(-x));
}

__device__ __forceinline__ void gload_lds16(const _Float16* g, const _Float16* l) {
    __builtin_amdgcn_global_load_lds(
        (const __attribute__((address_space(1))) void*)(uintptr_t)g,
        (__attribute__((address_space(3))) void*)(uintptr_t)l,
        16, 0, 0);
}

// fp32 -> fp16 arena conversion (x + all weights). 8 elems/thread.
__global__ __launch_bounds__(256) void cvt_k(
    const float* __restrict__ x, const float* __restrict__ inp_w,
    const float* __restrict__ in_proj_w, const float* __restrict__ xproj_w,
    const float* __restrict__ dt_w, const float* __restrict__ out_w,
    const float* __restrict__ outp_w, _Float16* __restrict__ dst)
{
    long i = ((long)blockIdx.x * 256 + threadIdx.x) * 8;
    const float* s;
    if      (i < E_INPW)   s = x         + (i - E_X);
    else if (i < E_INPROJ) s = inp_w     + (i - E_INPW);
    else if (i < E_XPROJ)  s = in_proj_w + (i - E_INPROJ);
    else if (i < E_DTW)    s = xproj_w   + (i - E_XPROJ);
    else if (i < E_OUTW)   s = dt_w      + (i - E_DTW);
    else if (i < E_OUTPW)  s = out_w     + (i - E_OUTW);
    else                   s = outp_w    + (i - E_OUTPW);
    float4 a = *(const float4*)s;
    float4 b = *(const float4*)(s + 4);
    half8 h;
    h[0]=(_Float16)a.x; h[1]=(_Float16)a.y; h[2]=(_Float16)a.z; h[3]=(_Float16)a.w;
    h[4]=(_Float16)b.x; h[5]=(_Float16)b.y; h[6]=(_Float16)b.z; h[7]=(_Float16)b.w;
    *(half8*)(dst + i) = h;
}

struct EpiP {
    float* o32;
    _Float16* o16;
    _Float16* o16b;
    const float* bias;
    const float* cw;
    const float* cb;
    const float* dtb;
    const float* Dp;
    const _Float16* xc;
    const _Float16* zs;
};

// C[M x N] = A[M x K(lda)] * W[N x K]^T, both fp16. Tile 128x128, BK=32,
// 4 waves x (4x4) 16x16x32 MFMAs, global_load_lds(16B) staging into
// double-buffered LDS (single barrier per K-iter: prefetch k+1 after the
// barrier, compute k -> load latency hidden behind compute).
// Epilogue (all EPI but 5): LDS slab transpose, line-contiguous stores.
template<int EPI>
__global__ __launch_bounds__(256) void gemm_k(
    const _Float16* __restrict__ A, const _Float16* __restrict__ W,
    int N, int K, int lda, int kChunk, EpiP ep)
{
    __shared__ __align__(16) char smem[36864];   // dbuf K-loop: 32 KB; epilogue: 4x9 KB slabs
    const int tid  = threadIdx.x;
    const int lane = tid & 63;
    const int wave = tid >> 6;
    const int wm = (wave >> 1) * 64;
    const int wn = (wave & 1) * 64;
    const int lr = lane & 15;
    const int lq = lane >> 4;
    const long tm = (long)blockIdx.y * 128;
    const int  tn = blockIdx.x * 128;

    // staging: slot p = wave*128 + c*64 + lane ; slot(r,cc) = r*4 + ((cc + (r>>1)) & 3)
    const int p0 = wave * 128 + lane;
    const int r0 = p0 >> 2, c0 = ((p0 & 3) - ((r0 >> 1) & 3)) & 3;
    const int p1 = p0 + 64;
    const int r1 = p1 >> 2, c1 = ((p1 & 3) - ((r1 >> 1) & 3)) & 3;

    const int kBeg = blockIdx.z * kChunk;
    const _Float16* a0 = A + (tm + r0) * (long)lda + kBeg + c0 * 8;
    const _Float16* a1 = A + (tm + r1) * (long)lda + kBeg + c1 * 8;
    const _Float16* w0 = W + (long)min(tn + r0, N - 1) * K + kBeg + c0 * 8;
    const _Float16* w1 = W + (long)min(tn + r1, N - 1) * K + kBeg + c1 * 8;

    floatx4 acc[4][4];
#pragma unroll
    for (int i = 0; i < 4; i++)
#pragma unroll
        for (int j = 0; j < 4; j++) acc[i][j] = (floatx4)0.0f;

    const int iters = kChunk / 32;
    // buffer b: As at smem + b*16384, Bs at smem + b*16384 + 8192
    auto stage = [&](int b) {
        _Float16* As = (_Float16*)(smem + b * 16384);
        _Float16* Bs = (_Float16*)(smem + b * 16384 + 8192);
        gload_lds16(a0, &As[wave * 1024]);
        gload_lds16(a1, &As[wave * 1024 + 512]);
        gload_lds16(w0, &Bs[wave * 1024]);
        gload_lds16(w1, &Bs[wave * 1024 + 512]);
        a0 += 32; a1 += 32; w0 += 32; w1 += 32;
    };

    stage(0);
    for (int it = 0; it < iters; it++) {
        __syncthreads();                      // buf[it&1] staging complete
        if (it + 1 < iters) stage((it + 1) & 1);
        const _Float16* As = (const _Float16*)(smem + (it & 1) * 16384);
        const _Float16* Bs = As + 4096;

        half8 af[4], bf[4];
#pragma unroll
        for (int i = 0; i < 4; i++) {
            int row = wm + i * 16 + lr;
            int slot = row * 4 + ((lq + (row >> 1)) & 3);
            af[i] = *(const half8*)&As[slot * 8];
        }
#pragma unroll
        for (int j = 0; j < 4; j++) {
            int row = wn + j * 16 + lr;
            int slot = row * 4 + ((lq + (row >> 1)) & 3);
            bf[j] = *(const half8*)&Bs[slot * 8];
        }
#pragma unroll
        for (int i = 0; i < 4; i++)
#pragma unroll
            for (int j = 0; j < 4; j++)
                acc[i][j] = __builtin_amdgcn_mfma_f32_16x16x32_f16(af[i], bf[j], acc[i][j], 0, 0, 0);
    }
    __syncthreads();   // protect slab (aliases K-loop buffers)

    if constexpr (EPI != 5) {
        // ---- line-contiguous epilogue via wave-private 64x72 LDS slab ----
        _Float16* slab = (_Float16*)(smem + wave * 9216);
#pragma unroll
        for (int i = 0; i < 4; i++)
#pragma unroll
            for (int j = 0; j < 4; j++)
#pragma unroll
                for (int p = 0; p < 4; p++)
                    slab[(i * 16 + lq * 4 + p) * 72 + j * 16 + lr] = (_Float16)acc[i][j][p];

        const int rsub = lane >> 3;       // row sub-index 0..7
        const int cch  = lane & 7;        // col chunk 0..7
        const int cb0  = tn + wn;
        const int n0   = cb0 + cch * 8;   // this lane's 8 columns (fixed)
        const long g0  = tm + wm;

        // per-lane channel-param preloads
        float bv[8], cwv[8], dtbv[8], dpv[8];
        if constexpr (EPI == 0) {
            float4 q0 = *(const float4*)&ep.bias[n0];
            float4 q1 = *(const float4*)&ep.bias[n0 + 4];
            bv[0]=q0.x; bv[1]=q0.y; bv[2]=q0.z; bv[3]=q0.w;
            bv[4]=q1.x; bv[5]=q1.y; bv[6]=q1.z; bv[7]=q1.w;
        }
        if constexpr (EPI == 1) {
            if (cb0 < DI) {
#pragma unroll
                for (int k = 0; k < 8; k++) cwv[k] = ep.cw[(n0 + k) * DC + 3];
                float4 q0 = *(const float4*)&ep.cb[n0];
                float4 q1 = *(const float4*)&ep.cb[n0 + 4];
                bv[0]=q0.x; bv[1]=q0.y; bv[2]=q0.z; bv[3]=q0.w;
                bv[4]=q1.x; bv[5]=q1.y; bv[6]=q1.z; bv[7]=q1.w;
            }
        }
        float bcv;
        if constexpr (EPI == 3) {
            float4 q0 = *(const float4*)&ep.dtb[n0];
            float4 q1 = *(const float4*)&ep.dtb[n0 + 4];
            dtbv[0]=q0.x; dtbv[1]=q0.y; dtbv[2]=q0.z; dtbv[3]=q0.w;
            dtbv[4]=q1.x; dtbv[5]=q1.y; dtbv[6]=q1.z; dtbv[7]=q1.w;
            float4 p0v = *(const float4*)&ep.Dp[n0];
            float4 p1v = *(const float4*)&ep.Dp[n0 + 4];
            dpv[0]=p0v.x; dpv[1]=p0v.y; dpv[2]=p0v.z; dpv[3]=p0v.w;
            dpv[4]=p1v.x; dpv[5]=p1v.y; dpv[6]=p1v.z; dpv[7]=p1v.w;
            // BC for this lane's row (g0+lane): Bm.Cm from xdbl (= A, lda 96)
            const half8* pp = (const half8*)(A + (g0 + lane) * 96 + DTR);
            half8 b0 = pp[0], b1 = pp[1], c0v = pp[2], c1v = pp[3];
            float s = 0.0f;
#pragma unroll
            for (int k = 0; k < 8; k++)
                s += (float)b0[k] * (float)c0v[k] + (float)b1[k] * (float)c1v[k];
            bcv = s;
        }

#pragma unroll
        for (int r = 0; r < 8; r++) {
            long g = g0 + r * 8 + rsub;
            half8 hv = *(const half8*)&slab[(r * 8 + rsub) * 72 + cch * 8];
            if constexpr (EPI == 0) {          // input: +bias -> h32 + h16
                float4 f0, f1; half8 o;
#pragma unroll
                for (int k = 0; k < 4; k++) {
                    float v = (float)hv[k] + bv[k];
                    (&f0.x)[k] = v; o[k] = (_Float16)v;
                }
#pragma unroll
                for (int k = 0; k < 4; k++) {
                    float v = (float)hv[k + 4] + bv[k + 4];
                    (&f1.x)[k] = v; o[k + 4] = (_Float16)v;
                }
                *(float4*)&ep.o32[g * DM + n0]     = f0;
                *(float4*)&ep.o32[g * DM + n0 + 4] = f1;
                *(half8*)&ep.o16[g * DM + n0] = o;
            } else if constexpr (EPI == 1) {   // inproj: conv+silu / silu
                half8 o;
                if (cb0 < DI) {
#pragma unroll
                    for (int k = 0; k < 8; k++) {
                        float s = (float)hv[k] * cwv[k] + bv[k];
                        o[k] = (_Float16)silu_f(s);
                    }
                    *(half8*)&ep.o16[g * DI + n0] = o;
                } else {
#pragma unroll
                    for (int k = 0; k < 8; k++) o[k] = (_Float16)silu_f((float)hv[k]);
                    *(half8*)&ep.o16b[g * DI + (n0 - DI)] = o;
                }
            } else if constexpr (EPI == 3) {   // dt: softplus, y = xc*(dt*BC+D)*zs
                float bc = __shfl(bcv, r * 8 + rsub, 64);
                half8 xcv = *(const half8*)&ep.xc[g * DI + n0];
                half8 zsv = *(const half8*)&ep.zs[g * DI + n0];
                half8 o;
#pragma unroll
                for (int k = 0; k < 8; k++) {
                    float dtv = (float)hv[k] + dtbv[k];
                    dtv = (dtv > 20.0f) ? dtv : log1pf(__expf(dtv));
                    float y = (float)xcv[k] * (dtv * bc + dpv[k]) * (float)zsv[k];
                    o[k] = (_Float16)y;
                }
                *(half8*)&ep.o16[g * DI + n0] = o;
            } else if constexpr (EPI == 4) {   // out -> lnin fp16 partial (z slabs)
                *(half8*)&ep.o16[((long)blockIdx.z * BATCH + g) * DM + n0] = hv;
            } else {                            // EPI 6: xproj split-K fp16 partials
                if (n0 < 96)
                    *(half8*)&ep.o16[((long)blockIdx.z * BATCH + g) * 96 + n0] = hv;
            }
        }
    } else {
        // ---- EPI 5 (final, N=128): scalar epilogue ----
#pragma unroll
        for (int i = 0; i < 4; i++) {
#pragma unroll
            for (int p = 0; p < 4; p++) {
                long m = tm + wm + i * 16 + lq * 4 + p;
#pragma unroll
                for (int j = 0; j < 4; j++) {
                    int n = tn + wn + j * 16 + lr;
                    if (n >= N) continue;
                    ep.o32[m * OUT_DIM + n] = acc[i][j][p] + ep.bias[n];
                }
            }
        }
    }
}

// reduce xproj split-K fp16 partials -> xdbl fp16
__global__ __launch_bounds__(256) void xred_k(
    const _Float16* __restrict__ part, _Float16* __restrict__ xdbl)
{
    long i = ((long)blockIdx.x * 256 + threadIdx.x) * 4;   // flat over BATCH*96
    float s0 = 0.f, s1 = 0.f, s2 = 0.f, s3 = 0.f;
#pragma unroll
    for (int z = 0; z < 8; z++) {
        half4 v = *(const half4*)&part[(long)z * BATCH * 96 + i];
        s0 += (float)v[0]; s1 += (float)v[1]; s2 += (float)v[2]; s3 += (float)v[3];
    }
    half4 h;
    h[0] = (_Float16)s0; h[1] = (_Float16)s1; h[2] = (_Float16)s2; h[3] = (_Float16)s3;
    *(half4*)&xdbl[i] = h;
}

// LayerNorm(lnin_z0 + lnin_z1) * g + b + residual -> h32, h16
__global__ __launch_bounds__(256) void ln_k(
    const _Float16* __restrict__ xin, const float* __restrict__ g, const float* __restrict__ b,
    float* __restrict__ h32, _Float16* __restrict__ h16)
{
    long row = blockIdx.x;
    const _Float16* x0 = xin + row * DM;
    const _Float16* x1 = xin + ((long)BATCH + row) * DM;
    int t = threadIdx.x;
    float v[4];
    float s = 0.0f, ss = 0.0f;
#pragma unroll
    for (int i = 0; i < 4; i++) {
        int c = t + i * 256;
        v[i] = (float)x0[c] + (float)x1[c];
        s += v[i];
        ss += v[i] * v[i];
    }
#pragma unroll
    for (int o = 32; o > 0; o >>= 1) {
        s  += __shfl_down(s, o, 64);
        ss += __shfl_down(ss, o, 64);
    }
    __shared__ float rs[4], rss[4];
    int wv = t >> 6, ln = t & 63;
    if (ln == 0) { rs[wv] = s; rss[wv] = ss; }
    __syncthreads();
    if (t == 0) {
        float S  = rs[0] + rs[1] + rs[2] + rs[3];
        float SS = rss[0] + rss[1] + rss[2] + rss[3];
        float mu = S / (float)DM;
        float var = SS / (float)DM - mu * mu;
        rs[0]  = mu;
        rss[0] = rsqrtf(var + 1e-5f);
    }
    __syncthreads();
    float mu = rs[0], rstd = rss[0];
#pragma unroll
    for (int i = 0; i < 4; i++) {
        int c = t + i * 256;
        float hv = h32[row * DM + c] + (v[i] - mu) * rstd * g[c] + b[c];
        h32[row * DM + c] = hv;
        h16[row * DM + c] = (_Float16)hv;
    }
}

extern "C" void kernel_launch(void* const* d_in, const int* in_sizes, int n_in,
                              void* d_out, int out_size, void* d_ws, size_t ws_size,
                              hipStream_t stream) {
    const float* x         = (const float*)d_in[0];
    const float* inp_w     = (const float*)d_in[1];
    const float* inp_b     = (const float*)d_in[2];
    const float* in_proj_w = (const float*)d_in[3];
    const float* conv_w    = (const float*)d_in[4];
    const float* conv_b    = (const float*)d_in[5];
    const float* xproj_w   = (const float*)d_in[6];
    const float* dt_w      = (const float*)d_in[7];
    const float* dt_b      = (const float*)d_in[8];
    // d_in[9] = A_log : unused (Ls==1, h0==0)
    const float* D_param   = (const float*)d_in[10];
    const float* out_w     = (const float*)d_in[11];
    const float* ln_g      = (const float*)d_in[12];
    const float* ln_b      = (const float*)d_in[13];
    const float* outp_w    = (const float*)d_in[14];
    const float* outp_b    = (const float*)d_in[15];

    char* ws = (char*)d_ws;
    _Float16* wf    = (_Float16*)ws;                      // fp16 arena, 55.84 MB
    float*    h32   = (float*)   (ws + (56u  << 20));     // 16 MB residual fp32
    _Float16* h16   = (_Float16*)(ws + (72u  << 20));     //  8 MB
    _Float16* xc16  = (_Float16*)(ws + (80u  << 20));     // 16 MB (y16 in place)
    _Float16* zs16  = (_Float16*)(ws + (96u  << 20));     // 16 MB
    _Float16* lnin16= (_Float16*)(ws + (96u  << 20));     // 16 MB (2 split-K slabs), aliases zs16
    _Float16* xdbl  = (_Float16*)(ws + (112u << 20));     // 768 KB
    _Float16* xpart = (_Float16*)(ws + (114u << 20));     // 6.3 MB split-K fp16 partials

    dim3 blk(256);
    EpiP ep;

    cvt_k<<<dim3((unsigned)(E_TOT / (256 * 8))), blk, 0, stream>>>(
        x, inp_w, in_proj_w, xproj_w, dt_w, out_w, outp_w, wf);

    // input GEMM: h = x @ inp_w^T + b   (N=1024, K=256)
    ep = EpiP{}; ep.bias = inp_b; ep.o32 = h32; ep.o16 = h16;
    gemm_k<0><<<dim3(DM / 128, BATCH / 128, 1), blk, 0, stream>>>(
        wf + E_X, wf + E_INPW, DM, IN_DIM, IN_DIM, IN_DIM, ep);

    for (int l = 0; l < NL; l++) {
        // inproj (N=4096, K=1024): fused conv+silu -> xc16, silu -> zs16
        ep = EpiP{}; ep.o16 = xc16; ep.o16b = zs16;
        ep.cw = conv_w + (size_t)l * DI * DC; ep.cb = conv_b + (size_t)l * DI;
        gemm_k<1><<<dim3(2 * DI / 128, BATCH / 128, 1), blk, 0, stream>>>(
            h16, wf + E_INPROJ + (size_t)l * 2 * DI * DM, 2 * DI, DM, DM, DM, ep);

        // xproj (N=96, K=2048) split-K=8 -> fp16 partials
        ep = EpiP{}; ep.o16 = xpart;
        gemm_k<6><<<dim3(1, BATCH / 128, 8), blk, 0, stream>>>(
            xc16, wf + E_XPROJ + (size_t)l * (DTR + 2 * DS_N) * DI,
            DTR + 2 * DS_N, DI, DI, DI / 8, ep);

        xred_k<<<dim3(BATCH * 96 / 4 / 256), blk, 0, stream>>>(xpart, xdbl);

        // dt GEMM (N=2048, K=64) + scan-collapse (BC computed inline) -> y16
        ep = EpiP{}; ep.o16 = xc16;
        ep.dtb = dt_b + (size_t)l * DI; ep.Dp = D_param + (size_t)l * DI;
        ep.xc = xc16; ep.zs = zs16;
        gemm_k<3><<<dim3(DI / 128, BATCH / 128, 1), blk, 0, stream>>>(
            xdbl, wf + E_DTW + (size_t)l * DI * DTR, DI, DTR, 96, DTR, ep);

        // out GEMM (N=1024, K=2048) split-K=2 -> lnin16 partial slabs
        ep = EpiP{}; ep.o16 = lnin16;
        gemm_k<4><<<dim3(DM / 128, BATCH / 128, 2), blk, 0, stream>>>(
            xc16, wf + E_OUTW + (size_t)l * DM * DI, DM, DI, DI, DI / 2, ep);

        // LayerNorm(sum of partials) + residual
        ln_k<<<dim3(BATCH), blk, 0, stream>>>(
            lnin16, ln_g + (size_t)l * DM, ln_b + (size_t)l * DM, h32, h16);
    }

    // final (N=128, K=1024) -> d_out
    ep = EpiP{}; ep.bias = outp_b; ep.o32 = (float*)d_out;
    gemm_k<5><<<dim3(1, BATCH / 128, 1), blk, 0, stream>>>(
        h16, wf + E_OUTPW, OUT_DIM, DM, DM, DM, ep);
}